// Round 7
// baseline (263.246 us; speedup 1.0000x reference)
//
#include <hip/hip_runtime.h>
#include <hip/hip_cooperative_groups.h>
#include <math.h>

namespace cg = cooperative_groups;

#define S_LEN 2048
#define BSZ 2
#define DM 512
#define NH 8
#define HD 64
#define RTOT (S_LEN*BSZ)             // 4096 rows, row r = s*BSZ + b
#define T_KEEP 32
#define ROW0 ((S_LEN - T_KEEP)*BSZ)  // 4032

typedef __attribute__((ext_vector_type(8))) _Float16 half8;
typedef __attribute__((ext_vector_type(4))) float floatx4;

__device__ __forceinline__ half8 pack8(float4 a, float4 b) {
    half8 h;
    h[0]=(_Float16)a.x; h[1]=(_Float16)a.y; h[2]=(_Float16)a.z; h[3]=(_Float16)a.w;
    h[4]=(_Float16)b.x; h[5]=(_Float16)b.y; h[6]=(_Float16)b.z; h[7]=(_Float16)b.w;
    return h;
}

// ================= PHASE BODIES (verbatim from the R6-passing kernels) ========

__device__ void mega_body(
    const float* __restrict__ x,
    const float* __restrict__ Wq, const float* __restrict__ Wk,
    const float* __restrict__ bq, const float* __restrict__ bk,
    const float* __restrict__ beta, const float* __restrict__ bo,
    float* __restrict__ spart, float* __restrict__ ssump,
    float* __restrict__ qsel, float* __restrict__ out,
    char* smem, int bid, int tid)
{
    const int w    = tid >> 6;
    const int lane = tid & 63;
    const int lrow = lane & 15;
    const int lk8  = lane >> 4;
    const int rc   = (bid & 7)*4 + (bid >> 6);
    const int h    = (bid >> 3) & 7;
    const int r0   = rc * 128;

    // background out fill: rows < ROW0 are just bo; 2016 float4 per block
    {
        const float4* b4 = (const float4*)bo;
        float4* o4 = (float4*)out + (size_t)bid*2016;
        const int base = bid*2016;
        #pragma unroll
        for (int i = 0; i < 8; ++i) {
            int idx = i*256 + tid;
            if (idx < 2016) o4[idx] = b4[(base + idx) & 127];
        }
    }

    const int jsub = lk8;          // row within 4-row staging chunk
    const int l15  = lrow;

    // stage W quarter 0 (fp32 -> fp16 -> ds_write; pos p = s ^ (j&15))
    #pragma unroll
    for (int i = 0; i < 8; ++i) {
        const int chunk = w*8 + i;
        const int j = chunk*4 + jsub;            // 0..63 = q (Wq), 64..127 = k (Wk)
        const int s = l15 ^ (j & 15);
        const float* src = (j < 64 ? Wq + (size_t)(h*HD + j)*DM
                                   : Wk + (size_t)(h*HD + j - 64)*DM) + s*8;
        float4 f0 = *(const float4*)src;
        float4 f1 = *(const float4*)(src + 4);
        *(half8*)(smem + chunk*1024 + jsub*256 + l15*16) = pack8(f0, f1);
    }

    const float* xA = x + (size_t)(r0 + w*16 + lrow)*DM + lk8*8;
    const float* xB = x + (size_t)(r0 + (w+4)*16 + lrow)*DM + lk8*8;

    half8 Aa[4], Ab[4];
    #pragma unroll
    for (int kc2 = 0; kc2 < 4; ++kc2) {
        Aa[kc2] = pack8(*(const float4*)(xA + kc2*32), *(const float4*)(xA + kc2*32 + 4));
        Ab[kc2] = pack8(*(const float4*)(xB + kc2*32), *(const float4*)(xB + kc2*32 + 4));
    }

    floatx4 acc[2][8];
    #pragma unroll
    for (int jt = 0; jt < 8; ++jt) { acc[0][jt] = (floatx4)0.f; acc[1][jt] = (floatx4)0.f; }

    __syncthreads();

    #pragma unroll
    for (int kq = 0; kq < 4; ++kq) {
        const char* buf = smem + (kq & 1)*32768;
        char* nb = smem + ((kq + 1) & 1)*32768;

        float4 WF0[8], WF1[8];
        if (kq < 3) {
            #pragma unroll
            for (int i = 0; i < 8; ++i) {
                const int j = (w*8 + i)*4 + jsub;
                const int s = l15 ^ (j & 15);
                const float* src = (j < 64 ? Wq + (size_t)(h*HD + j)*DM
                                           : Wk + (size_t)(h*HD + j - 64)*DM)
                                   + (kq+1)*128 + s*8;
                WF0[i] = *(const float4*)src;
                WF1[i] = *(const float4*)(src + 4);
            }
        }

        #pragma unroll
        for (int kc2 = 0; kc2 < 4; ++kc2) {
            #pragma unroll
            for (int jt = 0; jt < 8; ++jt) {
                const int j = jt*16 + lrow;
                const int slotp = (kc2*4 + lk8) ^ lrow;   // p = s ^ (j&15)
                half8 bf = *(const half8*)(buf + j*256 + slotp*16);
                acc[0][jt] = __builtin_amdgcn_mfma_f32_16x16x32_f16(Aa[kc2], bf, acc[0][jt], 0, 0, 0);
                acc[1][jt] = __builtin_amdgcn_mfma_f32_16x16x32_f16(Ab[kc2], bf, acc[1][jt], 0, 0, 0);
            }
            if (kq < 3) {
                Aa[kc2] = pack8(*(const float4*)(xA + (kq+1)*128 + kc2*32),
                                *(const float4*)(xA + (kq+1)*128 + kc2*32 + 4));
                Ab[kc2] = pack8(*(const float4*)(xB + (kq+1)*128 + kc2*32),
                                *(const float4*)(xB + (kq+1)*128 + kc2*32 + 4));
            }
        }

        if (kq < 3) {
            #pragma unroll
            for (int i = 0; i < 8; ++i)
                *(half8*)(nb + (w*8 + i)*1024 + jsub*256 + l15*16) = pack8(WF0[i], WF1[i]);
        }
        __syncthreads();
    }

    // epilogue: sigma = sigmoid((q+bq).(k+bk) * isc); qsel for selected rows
    float* s_sig = (float*)smem;
    float bqv[4], bkv[4];
    #pragma unroll
    for (int jt = 0; jt < 4; ++jt) {
        bqv[jt] = bq[h*HD + jt*16 + lrow];
        bkv[jt] = bk[h*HD + jt*16 + lrow];
    }
    const float isc = 1.0f / (8.0f * expf(beta[h]));

    #pragma unroll
    for (int t = 0; t < 2; ++t) {
        #pragma unroll
        for (int r = 0; r < 4; ++r) {
            float q[4]; float p = 0.f;
            #pragma unroll
            for (int jt = 0; jt < 4; ++jt) {
                float qv = acc[t][jt][r]   + bqv[jt];
                float kv = acc[t][jt+4][r] + bkv[jt];
                q[jt] = qv;
                p += qv * kv;
            }
            p += __shfl_xor(p, 1, 64);
            p += __shfl_xor(p, 2, 64);
            p += __shfl_xor(p, 4, 64);
            p += __shfl_xor(p, 8, 64);
            const int rowl = (w + t*4)*16 + lk8*4 + r;    // 0..127 within block
            if (lrow == 0)
                s_sig[rowl] = 1.0f / (1.0f + expf(-p * isc));
            if (rowl >= 126) {                            // s%64==63 rows (b=0,1)
                const int b = rowl & 1;
                float* qd = &qsel[((size_t)((b*NH + h)*T_KEEP) + rc)*64];
                #pragma unroll
                for (int jt = 0; jt < 4; ++jt) qd[jt*16 + lrow] = q[jt];
            }
        }
    }
    __syncthreads();

    // spart partial (PLAIN writes): thread = (b, 4-col group)
    {
        const int b  = tid & 1;
        const int cg2 = tid >> 1;
        const float* px = x + (size_t)(r0 + b)*DM + cg2*4;
        float a0=0.f, a1=0.f, a2=0.f, a3=0.f;
        #pragma unroll 16
        for (int si = 0; si < 64; ++si) {
            const float sg = s_sig[si*2 + b];
            const float4 xv = *(const float4*)(px + (size_t)(si*2)*DM);
            a0 += sg*xv.x; a1 += sg*xv.y; a2 += sg*xv.z; a3 += sg*xv.w;
        }
        float4 st; st.x = a0; st.y = a1; st.z = a2; st.w = a3;
        *(float4*)&spart[((size_t)(rc*2 + b)*8 + h)*512 + cg2*4] = st;
    }
    if (tid < 2) {
        float s = 0.f;
        for (int i = 0; i < 64; ++i) s += s_sig[i*2 + tid];
        ssump[(rc*2 + tid)*8 + h] = s;
    }
}

__device__ void kvc_body(
    const float* __restrict__ spart, const float* __restrict__ ssump,
    const float* __restrict__ qsel, const float* __restrict__ beta,
    const float* __restrict__ Wk, const float* __restrict__ bk,
    const float* __restrict__ Wv, const float* __restrict__ bv,
    float* __restrict__ vbar, float* __restrict__ coef,
    char* smem, int bid, int tid)
{
    const int z  = bid >> 1;
    const int kvv = bid & 1;
    const int b  = z >> 3;
    const int h  = z & 7;

    float* s_sb = (float*)smem;                         // 2 KB
    float (*s_red)[4] = (float(*)[4])(smem + 2048);     // 1 KB
    float* s_kb = (float*)(smem + 3072);                // 256 B
    float (*s_part)[8] = (float(*)[8])(smem + 3584);    // 1 KB
    float* s_S = (float*)(smem + 4608);

    // stage 0: sbar = sum_rc spart (unrolled -> 32 loads in flight)
    {
        const float2* sp = (const float2*)spart;
        float ax = 0.f, ay = 0.f;
        #pragma unroll
        for (int rcc = 0; rcc < 32; ++rcc) {
            float2 v = sp[((size_t)(rcc*2 + b)*8 + h)*256 + tid];
            ax += v.x; ay += v.y;
        }
        s_sb[tid*2] = ax; s_sb[tid*2+1] = ay;
    }
    {
        float sv = 0.f;
        if (tid < 32) sv = ssump[(tid*2 + b)*8 + h];
        if (tid < 64) {
            sv += __shfl_xor(sv, 1, 64);
            sv += __shfl_xor(sv, 2, 64);
            sv += __shfl_xor(sv, 4, 64);
            sv += __shfl_xor(sv, 8, 64);
            sv += __shfl_xor(sv, 16, 64);
            if (tid == 0) *s_S = sv;
        }
    }
    __syncthreads();
    const float S = *s_S;

    const float* W    = kvv ? Wv : Wk;
    const float* bvec = kvv ? bv : bk;
    {
        const int j = tid >> 2, kp = tid & 3;
        const float* wr = &W[(size_t)(h*HD + j)*DM + kp*128];
        float a = 0.f;
        #pragma unroll
        for (int k = 0; k < 128; k += 4) {
            float4 w4 = *(const float4*)&wr[k];
            int k0 = kp*128 + k;
            a += w4.x*s_sb[k0] + w4.y*s_sb[k0+1] + w4.z*s_sb[k0+2] + w4.w*s_sb[k0+3];
        }
        s_red[j][kp] = a;
    }
    __syncthreads();
    if (tid < 64) {
        float val = s_red[tid][0]+s_red[tid][1]+s_red[tid][2]+s_red[tid][3]
                  + bvec[h*HD + tid]*S;
        if (kvv) vbar[z*HD + tid] = val;
        else     s_kb[tid] = val;
    }
    if (!kvv) {
        __syncthreads();
        {
            const int wi = tid >> 3, jg = tid & 7;
            const float* qrow = &qsel[((size_t)z*T_KEEP + wi)*64 + jg*8];
            float4 q1 = *(const float4*)qrow;
            float4 q2 = *(const float4*)(qrow + 4);
            const int j0 = jg*8;
            float p = q1.x*s_kb[j0]   + q1.y*s_kb[j0+1] + q1.z*s_kb[j0+2] + q1.w*s_kb[j0+3]
                    + q2.x*s_kb[j0+4] + q2.y*s_kb[j0+5] + q2.z*s_kb[j0+6] + q2.w*s_kb[j0+7];
            s_part[wi][jg] = p;
        }
        __syncthreads();
        if (tid < T_KEEP) {
            float sc = 0.f;
            #pragma unroll
            for (int gg = 0; gg < 8; ++gg) sc += s_part[tid][gg];
            sc *= 1.0f / (8.0f * expf(beta[h]));
            float m = sc;
            #pragma unroll
            for (int off = 16; off > 0; off >>= 1) m = fmaxf(m, __shfl_xor(m, off, 64));
            m = fmaxf(m, 0.f);                        // sink logit = 0
            float e = expf(sc - m);
            float d = e;
            #pragma unroll
            for (int off = 16; off > 0; off >>= 1) d += __shfl_xor(d, off, 64);
            d += expf(-m);                            // sink term
            float c = e / d;
            if (tid == T_KEEP-1) c += 1.0f;           // iter-0 contribution
            coef[z*T_KEEP + tid] = c;
        }
    }
}

__device__ void gout_body(
    const float* __restrict__ coef, const float* __restrict__ vbar,
    const float* __restrict__ Wo, const float* __restrict__ bo,
    float* __restrict__ out, char* smem, int bid, int tid)
{
    const int b  = bid & 1;
    const int cc = bid >> 1;      // 0..31

    float (*s_cf)[T_KEEP] = (float(*)[T_KEEP])smem;          // 1 KB
    float* s_vb = (float*)(smem + 1024);                     // 2 KB
    float (*s_gp)[NH][2] = (float(*)[NH][2])(smem + 3072);   // 1 KB

    s_vb[tid]       = vbar[b*512 + tid];
    s_vb[tid + 256] = vbar[b*512 + 256 + tid];
    s_cf[tid >> 5][tid & 31] = coef[((size_t)(b*NH) + (tid >> 5))*T_KEEP + (tid & 31)];
    __syncthreads();

    {
        const int ci = tid & 15, hh = (tid >> 4) & 7, j2 = tid >> 7;
        const float* wr = &Wo[(size_t)(cc*16 + ci)*DM + hh*HD + j2*32];
        const float* vb = &s_vb[hh*HD + j2*32];
        float a = 0.f;
        #pragma unroll
        for (int j = 0; j < 32; j += 4) {
            float4 w4 = *(const float4*)&wr[j];
            a += w4.x*vb[j] + w4.y*vb[j+1] + w4.z*vb[j+2] + w4.w*vb[j+3];
        }
        s_gp[ci][hh][j2] = a;
    }
    __syncthreads();
    {
        const int ci = tid & 15;
        const float bov = bo[cc*16 + ci];
        #pragma unroll
        for (int hf = 0; hf < 2; ++hf) {
            const int wi = (tid >> 4) + hf*16;
            float v = bov;
            #pragma unroll
            for (int hh = 0; hh < NH; ++hh)
                v += s_cf[hh][wi] * (s_gp[ci][hh][0] + s_gp[ci][hh][1]);
            out[(size_t)(ROW0 + wi*2 + b)*DM + cc*16 + ci] = v;
        }
    }
}

// ---- single cooperative kernel: mega -> gridsync -> kvc -> gridsync -> gout --
__global__ __launch_bounds__(256, 1) void fused(
    const float* __restrict__ x,
    const float* __restrict__ Wq, const float* __restrict__ Wk,
    const float* __restrict__ Wv, const float* __restrict__ Wo,
    const float* __restrict__ bq, const float* __restrict__ bk,
    const float* __restrict__ bv, const float* __restrict__ bo,
    const float* __restrict__ beta,
    float* __restrict__ spart, float* __restrict__ ssump,
    float* __restrict__ qsel, float* __restrict__ vbar,
    float* __restrict__ coef, float* __restrict__ out)
{
    __shared__ __align__(16) char smem[65536];
    const int bid = blockIdx.x;
    const int tid = threadIdx.x;

    mega_body(x, Wq, Wk, bq, bk, beta, bo, spart, ssump, qsel, out, smem, bid, tid);

    __threadfence();
    cg::this_grid().sync();

    if (bid < 32)
        kvc_body(spart, ssump, qsel, beta, Wk, bk, Wv, bv, vbar, coef, smem, bid, tid);

    __threadfence();
    cg::this_grid().sync();

    if (bid < 64)
        gout_body(coef, vbar, Wo, bo, out, smem, bid, tid);
}

// ---- fallback 3-kernel chain (R6-proven) -------------------------------------
__global__ __launch_bounds__(256, 1) void megaK(
    const float* __restrict__ x,
    const float* __restrict__ Wq, const float* __restrict__ Wk,
    const float* __restrict__ bq, const float* __restrict__ bk,
    const float* __restrict__ beta, const float* __restrict__ bo,
    float* __restrict__ spart, float* __restrict__ ssump,
    float* __restrict__ qsel, float* __restrict__ out)
{
    __shared__ __align__(16) char smem[65536];
    mega_body(x, Wq, Wk, bq, bk, beta, bo, spart, ssump, qsel, out,
              smem, blockIdx.x, threadIdx.x);
}

__global__ __launch_bounds__(256) void kvcK(
    const float* __restrict__ spart, const float* __restrict__ ssump,
    const float* __restrict__ qsel, const float* __restrict__ beta,
    const float* __restrict__ Wk, const float* __restrict__ bk,
    const float* __restrict__ Wv, const float* __restrict__ bv,
    float* __restrict__ vbar, float* __restrict__ coef)
{
    __shared__ __align__(16) char smem[8192];
    kvc_body(spart, ssump, qsel, beta, Wk, bk, Wv, bv, vbar, coef,
             smem, blockIdx.x, threadIdx.x);
}

__global__ __launch_bounds__(256) void goutK(
    const float* __restrict__ coef, const float* __restrict__ vbar,
    const float* __restrict__ Wo, const float* __restrict__ bo,
    float* __restrict__ out)
{
    __shared__ __align__(16) char smem[8192];
    gout_body(coef, vbar, Wo, bo, out, smem, blockIdx.x, threadIdx.x);
}

extern "C" void kernel_launch(void* const* d_in, const int* in_sizes, int n_in,
                              void* d_out, int out_size, void* d_ws, size_t ws_size,
                              hipStream_t stream) {
    const float* x    = (const float*)d_in[0];
    const float* Wq   = (const float*)d_in[1];
    const float* bq   = (const float*)d_in[2];
    const float* Wk   = (const float*)d_in[3];
    const float* bk   = (const float*)d_in[4];
    const float* Wv   = (const float*)d_in[5];
    const float* bv   = (const float*)d_in[6];
    const float* Wo   = (const float*)d_in[7];
    const float* bo   = (const float*)d_in[8];
    const float* beta = (const float*)d_in[9];

    char* ws = (char*)d_ws;
    float* spart = (float*)(ws + 0);              // 1 MB   [rc][b][h][512]
    float* ssump = (float*)(ws + 1048576);        // 2 KB   [rc*2+b][h]
    float* qsel  = (float*)(ws + 1052672);        // 128 KB [z][32][64]
    float* vbar  = (float*)(ws + 1183744);        // 4 KB   [z][64]
    float* coef  = (float*)(ws + 1187840);        // 2 KB   [z][32]
    float* out   = (float*)d_out;

    void* kargs[] = {
        (void*)&x, (void*)&Wq, (void*)&Wk, (void*)&Wv, (void*)&Wo,
        (void*)&bq, (void*)&bk, (void*)&bv, (void*)&bo, (void*)&beta,
        (void*)&spart, (void*)&ssump, (void*)&qsel, (void*)&vbar,
        (void*)&coef, (void*)&out
    };
    hipError_t err = hipLaunchCooperativeKernel(
        reinterpret_cast<void*>(fused), dim3(256), dim3(256), kargs, 0, stream);
    if (err != hipSuccess) {
        // fallback: proven 3-kernel chain
        megaK<<<256, 256, 0, stream>>>(x, Wq, Wk, bq, bk, beta, bo,
                                       spart, ssump, qsel, out);
        kvcK<<<32, 256, 0, stream>>>(spart, ssump, qsel, beta,
                                     Wk, bk, Wv, bv, vbar, coef);
        goutK<<<64, 256, 0, stream>>>(coef, vbar, Wo, bo, out);
    }
}

// Round 8
// 118.521 us; speedup vs baseline: 2.2211x; 2.2211x over previous
//
#include <hip/hip_runtime.h>
#include <math.h>

#define S_LEN 2048
#define BSZ 2
#define DM 512
#define NH 8
#define HD 64
#define RTOT (S_LEN*BSZ)             // 4096 rows, row r = s*BSZ + b
#define T_KEEP 32
#define ROW0 ((S_LEN - T_KEEP)*BSZ)  // 4032

typedef __attribute__((ext_vector_type(8))) _Float16 half8;
typedef __attribute__((ext_vector_type(4))) float floatx4;

__device__ __forceinline__ half8 pack8(float4 a, float4 b) {
    half8 h;
    h[0]=(_Float16)a.x; h[1]=(_Float16)a.y; h[2]=(_Float16)a.z; h[3]=(_Float16)a.w;
    h[4]=(_Float16)b.x; h[5]=(_Float16)b.y; h[6]=(_Float16)b.z; h[7]=(_Float16)b.w;
    return h;
}

// ---- Kernel 1 (MEGA): fused convert + q|k GEMM + sigmoid + partials ----------
// grid 256 = (xcd-swizzled rc 0..31) x (h 0..7); 1 block/CU, 64KB LDS.
// Identical to the R6-passing kernel EXCEPT: bg-fill now covers ALL 4096 rows
// (tail rows init to bo, which tailk then atomically accumulates into).
__global__ __launch_bounds__(256, 1) void mega(
    const float* __restrict__ x,
    const float* __restrict__ Wq, const float* __restrict__ Wk,
    const float* __restrict__ bq, const float* __restrict__ bk,
    const float* __restrict__ beta, const float* __restrict__ bo,
    float* __restrict__ spart, float* __restrict__ ssump,
    float* __restrict__ qsel, float* __restrict__ out)
{
    __shared__ __align__(16) char smem[65536];   // 2 x 32KB W quarters; reused for sigma

    const int tid  = threadIdx.x;
    const int w    = tid >> 6;
    const int lane = tid & 63;
    const int lrow = lane & 15;
    const int lk8  = lane >> 4;
    const int bid  = blockIdx.x;
    const int rc   = (bid & 7)*4 + (bid >> 6);
    const int h    = (bid >> 3) & 7;
    const int r0   = rc * 128;

    // background out fill: ALL rows get bo (tail rows are then accumulated
    // atomically by tailk; kernel boundary guarantees ordering).
    // 2048 float4 per block x 256 blocks = full 4096x512.
    {
        const float4* b4 = (const float4*)bo;
        float4* o4 = (float4*)out + (size_t)bid*2048;
        const int base = bid*2048;
        #pragma unroll
        for (int i = 0; i < 8; ++i) {
            int idx = i*256 + tid;
            o4[idx] = b4[(base + idx) & 127];
        }
    }

    const int jsub = lk8;          // row within 4-row staging chunk
    const int l15  = lrow;

    // stage W quarter 0 (fp32 -> fp16 -> ds_write; pos p = s ^ (j&15))
    #pragma unroll
    for (int i = 0; i < 8; ++i) {
        const int chunk = w*8 + i;
        const int j = chunk*4 + jsub;            // 0..63 = q (Wq), 64..127 = k (Wk)
        const int s = l15 ^ (j & 15);
        const float* src = (j < 64 ? Wq + (size_t)(h*HD + j)*DM
                                   : Wk + (size_t)(h*HD + j - 64)*DM) + s*8;
        float4 f0 = *(const float4*)src;
        float4 f1 = *(const float4*)(src + 4);
        *(half8*)(smem + chunk*1024 + jsub*256 + l15*16) = pack8(f0, f1);
    }

    const float* xA = x + (size_t)(r0 + w*16 + lrow)*DM + lk8*8;
    const float* xB = x + (size_t)(r0 + (w+4)*16 + lrow)*DM + lk8*8;

    half8 Aa[4], Ab[4];
    #pragma unroll
    for (int kc2 = 0; kc2 < 4; ++kc2) {
        Aa[kc2] = pack8(*(const float4*)(xA + kc2*32), *(const float4*)(xA + kc2*32 + 4));
        Ab[kc2] = pack8(*(const float4*)(xB + kc2*32), *(const float4*)(xB + kc2*32 + 4));
    }

    floatx4 acc[2][8];
    #pragma unroll
    for (int jt = 0; jt < 8; ++jt) { acc[0][jt] = (floatx4)0.f; acc[1][jt] = (floatx4)0.f; }

    __syncthreads();

    #pragma unroll
    for (int kq = 0; kq < 4; ++kq) {
        const char* buf = smem + (kq & 1)*32768;
        char* nb = smem + ((kq + 1) & 1)*32768;

        // prefetch ONLY W for next quarter (issued before MFMAs, written after)
        float4 WF0[8], WF1[8];
        if (kq < 3) {
            #pragma unroll
            for (int i = 0; i < 8; ++i) {
                const int j = (w*8 + i)*4 + jsub;
                const int s = l15 ^ (j & 15);
                const float* src = (j < 64 ? Wq + (size_t)(h*HD + j)*DM
                                           : Wk + (size_t)(h*HD + j - 64)*DM)
                                   + (kq+1)*128 + s*8;
                WF0[i] = *(const float4*)src;
                WF1[i] = *(const float4*)(src + 4);
            }
        }

        #pragma unroll
        for (int kc2 = 0; kc2 < 4; ++kc2) {
            #pragma unroll
            for (int jt = 0; jt < 8; ++jt) {
                const int j = jt*16 + lrow;
                const int slotp = (kc2*4 + lk8) ^ lrow;   // p = s ^ (j&15)
                half8 bf = *(const half8*)(buf + j*256 + slotp*16);
                acc[0][jt] = __builtin_amdgcn_mfma_f32_16x16x32_f16(Aa[kc2], bf, acc[0][jt], 0, 0, 0);
                acc[1][jt] = __builtin_amdgcn_mfma_f32_16x16x32_f16(Ab[kc2], bf, acc[1][jt], 0, 0, 0);
            }
            if (kq < 3) {
                // refill A chunk kc2 for next quarter IN PLACE (last use above)
                Aa[kc2] = pack8(*(const float4*)(xA + (kq+1)*128 + kc2*32),
                                *(const float4*)(xA + (kq+1)*128 + kc2*32 + 4));
                Ab[kc2] = pack8(*(const float4*)(xB + (kq+1)*128 + kc2*32),
                                *(const float4*)(xB + (kq+1)*128 + kc2*32 + 4));
            }
        }

        if (kq < 3) {
            #pragma unroll
            for (int i = 0; i < 8; ++i)
                *(half8*)(nb + (w*8 + i)*1024 + jsub*256 + l15*16) = pack8(WF0[i], WF1[i]);
        }
        __syncthreads();
    }

    // epilogue: sigma = sigmoid((q+bq).(k+bk) * isc); qsel for selected rows
    float* s_sig = (float*)smem;
    float bqv[4], bkv[4];
    #pragma unroll
    for (int jt = 0; jt < 4; ++jt) {
        bqv[jt] = bq[h*HD + jt*16 + lrow];
        bkv[jt] = bk[h*HD + jt*16 + lrow];
    }
    const float isc = 1.0f / (8.0f * expf(beta[h]));

    #pragma unroll
    for (int t = 0; t < 2; ++t) {
        #pragma unroll
        for (int r = 0; r < 4; ++r) {
            float q[4]; float p = 0.f;
            #pragma unroll
            for (int jt = 0; jt < 4; ++jt) {
                float qv = acc[t][jt][r]   + bqv[jt];
                float kv = acc[t][jt+4][r] + bkv[jt];
                q[jt] = qv;
                p += qv * kv;
            }
            p += __shfl_xor(p, 1, 64);
            p += __shfl_xor(p, 2, 64);
            p += __shfl_xor(p, 4, 64);
            p += __shfl_xor(p, 8, 64);
            const int rowl = (w + t*4)*16 + lk8*4 + r;    // 0..127 within block
            if (lrow == 0)
                s_sig[rowl] = 1.0f / (1.0f + expf(-p * isc));
            if (rowl >= 126) {                            // s%64==63 rows (b=0,1)
                const int b = rowl & 1;
                float* qd = &qsel[((size_t)((b*NH + h)*T_KEEP) + rc)*64];
                #pragma unroll
                for (int jt = 0; jt < 4; ++jt) qd[jt*16 + lrow] = q[jt];
            }
        }
    }
    __syncthreads();

    // spart partial (PLAIN writes): thread = (b, 4-col group)
    {
        const int b  = tid & 1;
        const int cg = tid >> 1;
        const float* px = x + (size_t)(r0 + b)*DM + cg*4;
        float a0=0.f, a1=0.f, a2=0.f, a3=0.f;
        #pragma unroll 16
        for (int si = 0; si < 64; ++si) {
            const float sg = s_sig[si*2 + b];
            const float4 xv = *(const float4*)(px + (size_t)(si*2)*DM);
            a0 += sg*xv.x; a1 += sg*xv.y; a2 += sg*xv.z; a3 += sg*xv.w;
        }
        float4 st; st.x = a0; st.y = a1; st.z = a2; st.w = a3;
        *(float4*)&spart[((size_t)(rc*2 + b)*8 + h)*512 + cg*4] = st;
    }
    if (tid < 2) {
        float s = 0.f;
        for (int i = 0; i < 64; ++i) s += s_sig[i*2 + tid];
        ssump[(rc*2 + tid)*8 + h] = s;
    }
}

// ---- Kernel 2 (TAILK): per-z full tail, no cross-block deps ------------------
// grid 16 (z = b*8+h). sbar-reduce -> kbar+vbar -> coef softmax -> G ->
// atomicAdd coef[wi]*G[c] into out (out tail rows pre-initialized to bo by
// mega; atomicAdd is order-free so no sync needed; ~8-way contention/address).
__global__ __launch_bounds__(256) void tailk(
    const float* __restrict__ spart, const float* __restrict__ ssump,
    const float* __restrict__ qsel, const float* __restrict__ beta,
    const float* __restrict__ Wk, const float* __restrict__ bk,
    const float* __restrict__ Wv, const float* __restrict__ bv,
    const float* __restrict__ Wo, float* __restrict__ out)
{
    const int z = blockIdx.x;      // 0..15
    const int b = z >> 3;
    const int h = z & 7;
    const int tid = threadIdx.x;

    __shared__ float s_sb[DM];
    __shared__ float s_red2[128][2];
    __shared__ float s_kb[64], s_vb[64];
    __shared__ float s_part[T_KEEP][8];
    __shared__ float s_cf[T_KEEP];
    __shared__ float s_S;

    // stage 0: sbar = sum_rc spart (unrolled -> all 32 loads in flight)
    {
        const float2* sp = (const float2*)spart;
        float ax = 0.f, ay = 0.f;
        #pragma unroll
        for (int rcc = 0; rcc < 32; ++rcc) {
            float2 v = sp[((size_t)(rcc*2 + b)*8 + h)*256 + tid];
            ax += v.x; ay += v.y;
        }
        s_sb[tid*2] = ax; s_sb[tid*2+1] = ay;
    }
    {
        float sv = 0.f;
        if (tid < 32) sv = ssump[(tid*2 + b)*8 + h];
        if (tid < 64) {
            sv += __shfl_xor(sv, 1, 64);
            sv += __shfl_xor(sv, 2, 64);
            sv += __shfl_xor(sv, 4, 64);
            sv += __shfl_xor(sv, 8, 64);
            sv += __shfl_xor(sv, 16, 64);
            if (tid == 0) s_S = sv;
        }
    }
    __syncthreads();
    const float S = s_S;

    // stage 1: kbar AND vbar in one pass. idx = output (0..63 kbar, 64..127
    // vbar), kp = K-half. 64 float4 MACs per thread, fully unrolled.
    {
        const int idx  = tid >> 1;
        const int kp   = tid & 1;
        const int j    = idx & 63;
        const int kind = idx >> 6;               // 0 = kbar (Wk), 1 = vbar (Wv)
        const float* W = kind ? Wv : Wk;
        const float* wr = &W[(size_t)(h*HD + j)*DM + kp*256];
        const float* sb = &s_sb[kp*256];
        float a = 0.f;
        #pragma unroll
        for (int k = 0; k < 256; k += 4) {
            float4 w4 = *(const float4*)&wr[k];
            a += w4.x*sb[k] + w4.y*sb[k+1] + w4.z*sb[k+2] + w4.w*sb[k+3];
        }
        s_red2[idx][kp] = a;
    }
    __syncthreads();
    if (tid < 128) {
        const int j = tid & 63, kind = tid >> 6;
        float val = s_red2[tid][0] + s_red2[tid][1]
                  + (kind ? bv : bk)[h*HD + j]*S;
        if (kind) s_vb[j] = val;
        else      s_kb[j] = val;
    }
    __syncthreads();

    // stage 2: coef softmax with sink (8 threads per wi)
    {
        const int wi = tid >> 3, jg = tid & 7;
        const float* qrow = &qsel[((size_t)z*T_KEEP + wi)*64 + jg*8];
        float4 q1 = *(const float4*)qrow;
        float4 q2 = *(const float4*)(qrow + 4);
        const int j0 = jg*8;
        float p = q1.x*s_kb[j0]   + q1.y*s_kb[j0+1] + q1.z*s_kb[j0+2] + q1.w*s_kb[j0+3]
                + q2.x*s_kb[j0+4] + q2.y*s_kb[j0+5] + q2.z*s_kb[j0+6] + q2.w*s_kb[j0+7];
        s_part[wi][jg] = p;
    }
    __syncthreads();
    if (tid < T_KEEP) {
        float sc = 0.f;
        #pragma unroll
        for (int gg = 0; gg < 8; ++gg) sc += s_part[tid][gg];
        sc *= 1.0f / (8.0f * expf(beta[h]));
        float m = sc;
        #pragma unroll
        for (int off = 16; off > 0; off >>= 1) m = fmaxf(m, __shfl_xor(m, off, 64));
        m = fmaxf(m, 0.f);                        // sink logit = 0
        float e = expf(sc - m);
        float d = e;
        #pragma unroll
        for (int off = 16; off > 0; off >>= 1) d += __shfl_xor(d, off, 64);
        d += expf(-m);                            // sink term
        float c = e / d;
        if (tid == T_KEEP-1) c += 1.0f;           // iter-0 contribution
        s_cf[tid] = c;
    }
    __syncthreads();

    // stage 3: G[c] = Wo[c, h*64..]·vbar; out[row(wi,b), c] += cf[wi]*G[c]
    #pragma unroll
    for (int cc2 = 0; cc2 < 2; ++cc2) {
        const int c = cc2*256 + tid;
        const float* wr = &Wo[(size_t)c*DM + h*HD];
        float g = 0.f;
        #pragma unroll
        for (int j = 0; j < 64; j += 4) {
            float4 w4 = *(const float4*)&wr[j];
            g += w4.x*s_vb[j] + w4.y*s_vb[j+1] + w4.z*s_vb[j+2] + w4.w*s_vb[j+3];
        }
        #pragma unroll
        for (int wi = 0; wi < T_KEEP; ++wi)
            atomicAdd(&out[(size_t)(ROW0 + wi*2 + b)*DM + c], s_cf[wi]*g);
    }
}

extern "C" void kernel_launch(void* const* d_in, const int* in_sizes, int n_in,
                              void* d_out, int out_size, void* d_ws, size_t ws_size,
                              hipStream_t stream) {
    const float* x    = (const float*)d_in[0];
    const float* Wq   = (const float*)d_in[1];
    const float* bq   = (const float*)d_in[2];
    const float* Wk   = (const float*)d_in[3];
    const float* bk   = (const float*)d_in[4];
    const float* Wv   = (const float*)d_in[5];
    const float* bv   = (const float*)d_in[6];
    const float* Wo   = (const float*)d_in[7];
    const float* bo   = (const float*)d_in[8];
    const float* beta = (const float*)d_in[9];

    char* ws = (char*)d_ws;
    float* spart = (float*)(ws + 0);              // 1 MB   [rc][b][h][512]
    float* ssump = (float*)(ws + 1048576);        // 2 KB   [rc*2+b][h]
    float* qsel  = (float*)(ws + 1052672);        // 128 KB [z][32][64]
    float* out   = (float*)d_out;

    mega<<<256, 256, 0, stream>>>(x, Wq, Wk, bq, bk, beta, bo,
                                  spart, ssump, qsel, out);
    tailk<<<16, 256, 0, stream>>>(spart, ssump, qsel, beta,
                                  Wk, bk, Wv, bv, Wo, out);
}

// Round 9
// 112.437 us; speedup vs baseline: 2.3413x; 1.0541x over previous
//
#include <hip/hip_runtime.h>
#include <math.h>

#define S_LEN 2048
#define BSZ 2
#define DM 512
#define NH 8
#define HD 64
#define RTOT (S_LEN*BSZ)             // 4096 rows, row r = s*BSZ + b
#define T_KEEP 32
#define ROW0 ((S_LEN - T_KEEP)*BSZ)  // 4032

typedef __attribute__((ext_vector_type(8))) _Float16 half8;
typedef __attribute__((ext_vector_type(4))) float floatx4;

__device__ __forceinline__ half8 pack8(float4 a, float4 b) {
    half8 h;
    h[0]=(_Float16)a.x; h[1]=(_Float16)a.y; h[2]=(_Float16)a.z; h[3]=(_Float16)a.w;
    h[4]=(_Float16)b.x; h[5]=(_Float16)b.y; h[6]=(_Float16)b.z; h[7]=(_Float16)b.w;
    return h;
}

// ---- Kernel 1 (MEGA): fused convert + q|k GEMM + sigmoid + partials ----------
// grid 256 = (xcd-swizzled rc 0..31) x (h 0..7); 1 block/CU, 64KB LDS.
__global__ __launch_bounds__(256, 1) void mega(
    const float* __restrict__ x,
    const float* __restrict__ Wq, const float* __restrict__ Wk,
    const float* __restrict__ bq, const float* __restrict__ bk,
    const float* __restrict__ beta, const float* __restrict__ bo,
    float* __restrict__ spart, float* __restrict__ ssump,
    float* __restrict__ qsel, float* __restrict__ out)
{
    __shared__ __align__(16) char smem[65536];   // 2 x 32KB W quarters; reused for sigma

    const int tid  = threadIdx.x;
    const int w    = tid >> 6;
    const int lane = tid & 63;
    const int lrow = lane & 15;
    const int lk8  = lane >> 4;
    const int bid  = blockIdx.x;
    const int rc   = (bid & 7)*4 + (bid >> 6);
    const int h    = (bid >> 3) & 7;
    const int r0   = rc * 128;

    // background out fill: rows < ROW0 are just bo; 2016 float4 per block
    {
        const float4* b4 = (const float4*)bo;
        float4* o4 = (float4*)out + (size_t)bid*2016;
        const int base = bid*2016;
        #pragma unroll
        for (int i = 0; i < 8; ++i) {
            int idx = i*256 + tid;
            if (idx < 2016) o4[idx] = b4[(base + idx) & 127];
        }
    }

    const int jsub = lk8;          // row within 4-row staging chunk
    const int l15  = lrow;

    // ---- stage W quarter 0 (fp32 load -> fp16 -> ds_write; pos p = s ^ (j&15),
    //      realized by picking source slot s = l15 ^ (j&15), writing at l15) ----
    #pragma unroll
    for (int i = 0; i < 8; ++i) {
        const int chunk = w*8 + i;
        const int j = chunk*4 + jsub;            // 0..63 = q (Wq), 64..127 = k (Wk)
        const int s = l15 ^ (j & 15);
        const float* src = (j < 64 ? Wq + (size_t)(h*HD + j)*DM
                                   : Wk + (size_t)(h*HD + j - 64)*DM) + s*8;
        float4 f0 = *(const float4*)src;
        float4 f1 = *(const float4*)(src + 4);
        *(half8*)(smem + chunk*1024 + jsub*256 + l15*16) = pack8(f0, f1);
    }

    // A pointers (fp32 x)
    const float* xA = x + (size_t)(r0 + w*16 + lrow)*DM + lk8*8;
    const float* xB = x + (size_t)(r0 + (w+4)*16 + lrow)*DM + lk8*8;

    half8 Aa[4], Ab[4];
    #pragma unroll
    for (int kc2 = 0; kc2 < 4; ++kc2) {
        Aa[kc2] = pack8(*(const float4*)(xA + kc2*32), *(const float4*)(xA + kc2*32 + 4));
        Ab[kc2] = pack8(*(const float4*)(xB + kc2*32), *(const float4*)(xB + kc2*32 + 4));
    }

    floatx4 acc[2][8];
    #pragma unroll
    for (int jt = 0; jt < 8; ++jt) { acc[0][jt] = (floatx4)0.f; acc[1][jt] = (floatx4)0.f; }

    __syncthreads();

    #pragma unroll
    for (int kq = 0; kq < 4; ++kq) {
        const char* buf = smem + (kq & 1)*32768;
        char* nb = smem + ((kq + 1) & 1)*32768;

        // prefetch ONLY W for next quarter (issued before MFMAs, written after)
        float4 WF0[8], WF1[8];
        if (kq < 3) {
            #pragma unroll
            for (int i = 0; i < 8; ++i) {
                const int j = (w*8 + i)*4 + jsub;
                const int s = l15 ^ (j & 15);
                const float* src = (j < 64 ? Wq + (size_t)(h*HD + j)*DM
                                           : Wk + (size_t)(h*HD + j - 64)*DM)
                                   + (kq+1)*128 + s*8;
                WF0[i] = *(const float4*)src;
                WF1[i] = *(const float4*)(src + 4);
            }
        }

        #pragma unroll
        for (int kc2 = 0; kc2 < 4; ++kc2) {
            #pragma unroll
            for (int jt = 0; jt < 8; ++jt) {
                const int j = jt*16 + lrow;
                const int slotp = (kc2*4 + lk8) ^ lrow;   // p = s ^ (j&15)
                half8 bf = *(const half8*)(buf + j*256 + slotp*16);
                acc[0][jt] = __builtin_amdgcn_mfma_f32_16x16x32_f16(Aa[kc2], bf, acc[0][jt], 0, 0, 0);
                acc[1][jt] = __builtin_amdgcn_mfma_f32_16x16x32_f16(Ab[kc2], bf, acc[1][jt], 0, 0, 0);
            }
            if (kq < 3) {
                // refill A chunk kc2 for next quarter IN PLACE (last use was above)
                Aa[kc2] = pack8(*(const float4*)(xA + (kq+1)*128 + kc2*32),
                                *(const float4*)(xA + (kq+1)*128 + kc2*32 + 4));
                Ab[kc2] = pack8(*(const float4*)(xB + (kq+1)*128 + kc2*32),
                                *(const float4*)(xB + (kq+1)*128 + kc2*32 + 4));
            }
        }

        if (kq < 3) {
            #pragma unroll
            for (int i = 0; i < 8; ++i)
                *(half8*)(nb + (w*8 + i)*1024 + jsub*256 + l15*16) = pack8(WF0[i], WF1[i]);
        }
        __syncthreads();
    }

    // ---- epilogue: sigma = sigmoid((q+bq).(k+bk) * isc); qsel for selected rows
    float* s_sig = (float*)smem;     // W no longer needed; reuse LDS
    float bqv[4], bkv[4];
    #pragma unroll
    for (int jt = 0; jt < 4; ++jt) {
        bqv[jt] = bq[h*HD + jt*16 + lrow];
        bkv[jt] = bk[h*HD + jt*16 + lrow];
    }
    const float isc = 1.0f / (8.0f * expf(beta[h]));

    #pragma unroll
    for (int t = 0; t < 2; ++t) {
        #pragma unroll
        for (int r = 0; r < 4; ++r) {
            float q[4]; float p = 0.f;
            #pragma unroll
            for (int jt = 0; jt < 4; ++jt) {
                float qv = acc[t][jt][r]   + bqv[jt];
                float kv = acc[t][jt+4][r] + bkv[jt];
                q[jt] = qv;
                p += qv * kv;
            }
            p += __shfl_xor(p, 1, 64);
            p += __shfl_xor(p, 2, 64);
            p += __shfl_xor(p, 4, 64);
            p += __shfl_xor(p, 8, 64);
            const int rowl = (w + t*4)*16 + lk8*4 + r;    // 0..127 within block
            if (lrow == 0)
                s_sig[rowl] = 1.0f / (1.0f + expf(-p * isc));
            if (rowl >= 126) {                            // s%64==63 rows (b=0,1)
                const int b = rowl & 1;
                float* qd = &qsel[((size_t)((b*NH + h)*T_KEEP) + rc)*64];
                #pragma unroll
                for (int jt = 0; jt < 4; ++jt) qd[jt*16 + lrow] = q[jt];
            }
        }
    }
    __syncthreads();

    // ---- spart partial (PLAIN writes, no atomics): thread = (b, 4-col group)
    {
        const int b  = tid & 1;
        const int cg = tid >> 1;
        const float* px = x + (size_t)(r0 + b)*DM + cg*4;
        float a0=0.f, a1=0.f, a2=0.f, a3=0.f;
        #pragma unroll 16
        for (int si = 0; si < 64; ++si) {
            const float sg = s_sig[si*2 + b];
            const float4 xv = *(const float4*)(px + (size_t)(si*2)*DM);
            a0 += sg*xv.x; a1 += sg*xv.y; a2 += sg*xv.z; a3 += sg*xv.w;
        }
        float4 st; st.x = a0; st.y = a1; st.z = a2; st.w = a3;
        *(float4*)&spart[((size_t)(rc*2 + b)*8 + h)*512 + cg*4] = st;
    }
    if (tid < 2) {
        float s = 0.f;
        for (int i = 0; i < 64; ++i) s += s_sig[i*2 + tid];
        ssump[(rc*2 + tid)*8 + h] = s;
    }
}

// ---- Kernel 2: spart-reduce -> kbar/vbar -> coef (grid 32 = z x {k,v}) ------
__global__ __launch_bounds__(256) void kvc(
    const float* __restrict__ spart, const float* __restrict__ ssump,
    const float* __restrict__ qsel, const float* __restrict__ beta,
    const float* __restrict__ Wk, const float* __restrict__ bk,
    const float* __restrict__ Wv, const float* __restrict__ bv,
    float* __restrict__ vbar, float* __restrict__ coef)
{
    const int z  = blockIdx.x >> 1;
    const int kv = blockIdx.x & 1;
    const int b  = z >> 3;
    const int h  = z & 7;
    const int tid = threadIdx.x;

    __shared__ float s_sb[DM];
    __shared__ float s_red[64][4];
    __shared__ float s_kb[64];
    __shared__ float s_part[T_KEEP][8];
    __shared__ float s_S;

    // stage 0: sbar = sum_rc spart. UNROLLED so all 32 loads are in flight
    {
        const float2* sp = (const float2*)spart;
        float ax = 0.f, ay = 0.f;
        #pragma unroll
        for (int rcc = 0; rcc < 32; ++rcc) {
            float2 v = sp[((size_t)(rcc*2 + b)*8 + h)*256 + tid];
            ax += v.x; ay += v.y;
        }
        s_sb[tid*2] = ax; s_sb[tid*2+1] = ay;
    }
    {
        float sv = 0.f;
        if (tid < 32) sv = ssump[(tid*2 + b)*8 + h];
        if (tid < 64) {
            sv += __shfl_xor(sv, 1, 64);
            sv += __shfl_xor(sv, 2, 64);
            sv += __shfl_xor(sv, 4, 64);
            sv += __shfl_xor(sv, 8, 64);
            sv += __shfl_xor(sv, 16, 64);
            if (tid == 0) s_S = sv;
        }
    }
    __syncthreads();
    const float S = s_S;

    const float* W    = kv ? Wv : Wk;
    const float* bvec = kv ? bv : bk;
    {
        const int j = tid >> 2, kp = tid & 3;
        const float* wr = &W[(size_t)(h*HD + j)*DM + kp*128];
        float a = 0.f;
        #pragma unroll
        for (int k = 0; k < 128; k += 4) {
            float4 w4 = *(const float4*)&wr[k];
            int k0 = kp*128 + k;
            a += w4.x*s_sb[k0] + w4.y*s_sb[k0+1] + w4.z*s_sb[k0+2] + w4.w*s_sb[k0+3];
        }
        s_red[j][kp] = a;
    }
    __syncthreads();
    if (tid < 64) {
        float val = s_red[tid][0]+s_red[tid][1]+s_red[tid][2]+s_red[tid][3]
                  + bvec[h*HD + tid]*S;
        if (kv) vbar[z*HD + tid] = val;
        else    s_kb[tid] = val;
    }
    if (kv) return;
    __syncthreads();
    {
        const int wi = tid >> 3, jg = tid & 7;
        const float* qrow = &qsel[((size_t)z*T_KEEP + wi)*64 + jg*8];
        float4 q1 = *(const float4*)qrow;
        float4 q2 = *(const float4*)(qrow + 4);
        const int j0 = jg*8;
        float p = q1.x*s_kb[j0]   + q1.y*s_kb[j0+1] + q1.z*s_kb[j0+2] + q1.w*s_kb[j0+3]
                + q2.x*s_kb[j0+4] + q2.y*s_kb[j0+5] + q2.z*s_kb[j0+6] + q2.w*s_kb[j0+7];
        s_part[wi][jg] = p;
    }
    __syncthreads();
    if (tid < T_KEEP) {
        float sc = 0.f;
        #pragma unroll
        for (int gg = 0; gg < 8; ++gg) sc += s_part[tid][gg];
        sc *= 1.0f / (8.0f * expf(beta[h]));
        float m = sc;
        #pragma unroll
        for (int off = 16; off > 0; off >>= 1) m = fmaxf(m, __shfl_xor(m, off, 64));
        m = fmaxf(m, 0.f);                        // sink logit = 0
        float e = expf(sc - m);
        float d = e;
        #pragma unroll
        for (int off = 16; off > 0; off >>= 1) d += __shfl_xor(d, off, 64);
        d += expf(-m);                            // sink term
        float c = e / d;
        if (tid == T_KEEP-1) c += 1.0f;           // iter-0 contribution
        coef[z*T_KEEP + tid] = c;
    }
}

// ---- Kernel 3: fused G + output combine --------------------------------------
// grid 64 (b x 32 col-chunks of 16). out[b,wi,c] = bo[c] + sum_h coef*G[h,c]
__global__ __launch_bounds__(256) void gout(
    const float* __restrict__ coef, const float* __restrict__ vbar,
    const float* __restrict__ Wo, const float* __restrict__ bo,
    float* __restrict__ out)
{
    const int b  = blockIdx.x & 1;
    const int cc = blockIdx.x >> 1;      // 0..31
    const int tid = threadIdx.x;

    __shared__ float s_cf[NH][T_KEEP];
    __shared__ float s_vb[NH*HD];
    __shared__ float s_gp[16][NH][2];

    s_vb[tid]       = vbar[b*512 + tid];
    s_vb[tid + 256] = vbar[b*512 + 256 + tid];
    s_cf[tid >> 5][tid & 31] = coef[((size_t)(b*NH) + (tid >> 5))*T_KEEP + (tid & 31)];
    __syncthreads();

    {
        const int ci = tid & 15, hh = (tid >> 4) & 7, j2 = tid >> 7;
        const float* wr = &Wo[(size_t)(cc*16 + ci)*DM + hh*HD + j2*32];
        const float* vb = &s_vb[hh*HD + j2*32];
        float a = 0.f;
        #pragma unroll
        for (int j = 0; j < 32; j += 4) {
            float4 w4 = *(const float4*)&wr[j];
            a += w4.x*vb[j] + w4.y*vb[j+1] + w4.z*vb[j+2] + w4.w*vb[j+3];
        }
        s_gp[ci][hh][j2] = a;
    }
    __syncthreads();
    {
        const int ci = tid & 15;
        const float bov = bo[cc*16 + ci];
        #pragma unroll
        for (int hf = 0; hf < 2; ++hf) {
            const int wi = (tid >> 4) + hf*16;
            float v = bov;
            #pragma unroll
            for (int hh = 0; hh < NH; ++hh)
                v += s_cf[hh][wi] * (s_gp[ci][hh][0] + s_gp[ci][hh][1]);
            out[(size_t)(ROW0 + wi*2 + b)*DM + cc*16 + ci] = v;
        }
    }
}

extern "C" void kernel_launch(void* const* d_in, const int* in_sizes, int n_in,
                              void* d_out, int out_size, void* d_ws, size_t ws_size,
                              hipStream_t stream) {
    const float* x    = (const float*)d_in[0];
    const float* Wq   = (const float*)d_in[1];
    const float* bq   = (const float*)d_in[2];
    const float* Wk   = (const float*)d_in[3];
    const float* bk   = (const float*)d_in[4];
    const float* Wv   = (const float*)d_in[5];
    const float* bv   = (const float*)d_in[6];
    const float* Wo   = (const float*)d_in[7];
    const float* bo   = (const float*)d_in[8];
    const float* beta = (const float*)d_in[9];

    char* ws = (char*)d_ws;
    float* spart = (float*)(ws + 0);              // 1 MB   [rc][b][h][512]
    float* ssump = (float*)(ws + 1048576);        // 2 KB   [rc*2+b][h]
    float* qsel  = (float*)(ws + 1052672);        // 128 KB [z][32][64]
    float* vbar  = (float*)(ws + 1183744);        // 4 KB   [z][64]
    float* coef  = (float*)(ws + 1187840);        // 2 KB   [z][32]
    float* out   = (float*)d_out;

    mega<<<256, 256, 0, stream>>>(x, Wq, Wk, bq, bk, beta, bo,
                                  spart, ssump, qsel, out);
    kvc<<<32, 256, 0, stream>>>(spart, ssump, qsel, beta,
                                Wk, bk, Wv, bv, vbar, coef);
    gout<<<64, 256, 0, stream>>>(coef, vbar, Wo, bo, out);
}